// Round 1
// baseline (83.225 us; speedup 1.0000x reference)
//
#include <hip/hip_runtime.h>
#include <hip/hip_bf16.h>

#define BATCH 4096
#define DIM   128
// TEMP = 0.25 -> 1/T = 4; 4*log2(e):
#define EXP_SCALE 5.770780163555854f

typedef __bf16 bf16_t;
typedef __bf16 bf16x8 __attribute__((ext_vector_type(8)));
typedef float  f32x4  __attribute__((ext_vector_type(4)));

// ---------------------------------------------------------------------------
// Kernel A: per row k, normalize emb_i[k] and emb_j[k] (fp32), write bf16
// z_i, z_j to workspace, and pos[k] = cos-sim(emb_i[k], emb_j[k]) in fp32.
// One wave per row; lane holds 2 consecutive floats of each input row.
// ---------------------------------------------------------------------------
__global__ __launch_bounds__(256) void normalize_kernel(
    const float* __restrict__ emb_i, const float* __restrict__ emb_j,
    bf16_t* __restrict__ zi, bf16_t* __restrict__ zj, float* __restrict__ pos)
{
    int wave = threadIdx.x >> 6;
    int lane = threadIdx.x & 63;
    int k = blockIdx.x * 4 + wave;

    const float2* ei = (const float2*)(emb_i + (size_t)k * DIM);
    const float2* ej = (const float2*)(emb_j + (size_t)k * DIM);
    float2 a = ei[lane];
    float2 b = ej[lane];

    float sii = a.x * a.x + a.y * a.y;
    float sjj = b.x * b.x + b.y * b.y;
    float sij = a.x * b.x + a.y * b.y;
#pragma unroll
    for (int m = 1; m < 64; m <<= 1) {
        sii += __shfl_xor(sii, m);
        sjj += __shfl_xor(sjj, m);
        sij += __shfl_xor(sij, m);
    }
    float inv_i = 1.0f / fmaxf(sqrtf(sii), 1e-12f);
    float inv_j = 1.0f / fmaxf(sqrtf(sjj), 1e-12f);

    struct bf16_2 { bf16_t x, y; };
    bf16_2 pi, pj;
    pi.x = (bf16_t)(a.x * inv_i);  pi.y = (bf16_t)(a.y * inv_i);
    pj.x = (bf16_t)(b.x * inv_j);  pj.y = (bf16_t)(b.y * inv_j);
    ((bf16_2*)(zi + (size_t)k * DIM))[lane] = pi;
    ((bf16_2*)(zj + (size_t)k * DIM))[lane] = pj;

    if (lane == 0) pos[k] = sij * inv_i * inv_j;
}

// ---------------------------------------------------------------------------
// Kernel B: 128x128 tile of S = Zi * Zj^T per block (grid 32x32).
// bf16 MFMA 16x16x32, K=128 in 4 steps. Epilogue: e = exp(4*s), accumulate
// per-lane row/col partials, shfl-reduce, atomicAdd into rowDenom/colDenom.
// LDS rows padded 128->136 elems (row stride 272 B = 68 banks -> 2-way
// conflict only, which is free; 272 B is 16B-aligned so b128 reads work).
// ---------------------------------------------------------------------------
__global__ __launch_bounds__(256) void gemm_exp_kernel(
    const bf16_t* __restrict__ zi, const bf16_t* __restrict__ zj,
    float* __restrict__ rowDenom, float* __restrict__ colDenom)
{
    __shared__ __align__(16) bf16_t zi_s[128][136];
    __shared__ __align__(16) bf16_t zj_s[128][136];

    const int tid = threadIdx.x;
    const int ti = blockIdx.x, tj = blockIdx.y;

    // Stage 128x128 bf16 of each matrix: 2048 16B-chunks / matrix, 8 iters.
#pragma unroll
    for (int it = 0; it < 8; ++it) {
        int c = it * 256 + tid;
        int row = c >> 4;          // 16 chunks per row
        int col = (c & 15) << 3;   // 8 bf16 per chunk
        *(uint4*)&zi_s[row][col] =
            *(const uint4*)(zi + ((size_t)(ti * 128 + row)) * DIM + col);
        *(uint4*)&zj_s[row][col] =
            *(const uint4*)(zj + ((size_t)(tj * 128 + row)) * DIM + col);
    }
    __syncthreads();

    const int wave = tid >> 6;
    const int lane = tid & 63;
    const int l15  = lane & 15;
    const int quad = lane >> 4;

    const f32x4 vzero = {0.f, 0.f, 0.f, 0.f};
    f32x4 acc[2][8];
#pragma unroll
    for (int rt = 0; rt < 2; ++rt)
#pragma unroll
        for (int ct = 0; ct < 8; ++ct) acc[rt][ct] = vzero;

#pragma unroll
    for (int ks = 0; ks < 4; ++ks) {
        int k0 = ks * 32 + quad * 8;
        bf16x8 afrag[2], bfrag[8];
#pragma unroll
        for (int rt = 0; rt < 2; ++rt)
            afrag[rt] = *(const bf16x8*)&zi_s[(wave * 2 + rt) * 16 + l15][k0];
#pragma unroll
        for (int ct = 0; ct < 8; ++ct)
            bfrag[ct] = *(const bf16x8*)&zj_s[ct * 16 + l15][k0];
#pragma unroll
        for (int rt = 0; rt < 2; ++rt)
#pragma unroll
            for (int ct = 0; ct < 8; ++ct)
                acc[rt][ct] = __builtin_amdgcn_mfma_f32_16x16x32_bf16(
                    afrag[rt], bfrag[ct], acc[rt][ct], 0, 0, 0);
    }

    // Epilogue: exp and partial sums.
    float rowPart[2][4] = {{0.f, 0.f, 0.f, 0.f}, {0.f, 0.f, 0.f, 0.f}};
    float colPart[8]    = {0.f, 0.f, 0.f, 0.f, 0.f, 0.f, 0.f, 0.f};
#pragma unroll
    for (int rt = 0; rt < 2; ++rt)
#pragma unroll
        for (int ct = 0; ct < 8; ++ct)
#pragma unroll
            for (int r = 0; r < 4; ++r) {
                float e = exp2f(acc[rt][ct][r] * EXP_SCALE);
                rowPart[rt][r] += e;   // row = (wave*2+rt)*16 + quad*4 + r
                colPart[ct]    += e;   // col = ct*16 + l15
            }

    // Row sums: reduce across the 16 lanes sharing a row (bits 0..3).
#pragma unroll
    for (int rt = 0; rt < 2; ++rt)
#pragma unroll
        for (int r = 0; r < 4; ++r) {
            float v = rowPart[rt][r];
            v += __shfl_xor(v, 1);
            v += __shfl_xor(v, 2);
            v += __shfl_xor(v, 4);
            v += __shfl_xor(v, 8);
            if (l15 == 0) {
                int grow = ti * 128 + (wave * 2 + rt) * 16 + quad * 4 + r;
                atomicAdd(&rowDenom[grow], v);
            }
        }

    // Col sums: reduce across the 4 quads (bits 4..5).
#pragma unroll
    for (int ct = 0; ct < 8; ++ct) {
        float v = colPart[ct];
        v += __shfl_xor(v, 16);
        v += __shfl_xor(v, 32);
        if (quad == 0) {
            int gcol = tj * 128 + ct * 16 + l15;
            atomicAdd(&colDenom[gcol], v);
        }
    }
}

// ---------------------------------------------------------------------------
// Kernel C: loss = (1/2B) * sum_k [log rowDenom_k + log colDenom_k - 8*pos_k]
// ---------------------------------------------------------------------------
__global__ __launch_bounds__(256) void finalize_kernel(
    const float* __restrict__ rowDenom, const float* __restrict__ colDenom,
    const float* __restrict__ pos, float* __restrict__ out)
{
    int tid = threadIdx.x;
    float acc = 0.f;
    for (int k = tid; k < BATCH; k += 256)
        acc += logf(rowDenom[k]) + logf(colDenom[k]) - 8.0f * pos[k];
#pragma unroll
    for (int m = 1; m < 64; m <<= 1) acc += __shfl_xor(acc, m);
    __shared__ float red[4];
    if ((tid & 63) == 0) red[tid >> 6] = acc;
    __syncthreads();
    if (tid == 0)
        out[0] = (red[0] + red[1] + red[2] + red[3]) * (1.0f / (2.0f * BATCH));
}

extern "C" void kernel_launch(void* const* d_in, const int* in_sizes, int n_in,
                              void* d_out, int out_size, void* d_ws, size_t ws_size,
                              hipStream_t stream) {
    const float* emb_i = (const float*)d_in[0];
    const float* emb_j = (const float*)d_in[1];
    float* out = (float*)d_out;

    char* ws = (char*)d_ws;
    bf16_t* zi       = (bf16_t*)(ws);                       // 1 MB
    bf16_t* zj       = (bf16_t*)(ws + (1u << 20));          // 1 MB
    float*  rowDenom = (float*)(ws + (2u << 20));           // 16 KB
    float*  colDenom = rowDenom + BATCH;                    // 16 KB
    float*  pos      = colDenom + BATCH;                    // 16 KB

    hipMemsetAsync(rowDenom, 0, 2 * BATCH * sizeof(float), stream);
    normalize_kernel<<<BATCH / 4, 256, 0, stream>>>(emb_i, emb_j, zi, zj, pos);
    gemm_exp_kernel<<<dim3(32, 32), 256, 0, stream>>>(zi, zj, rowDenom, colDenom);
    finalize_kernel<<<1, 256, 0, stream>>>(rowDenom, colDenom, pos, out);
}